// Round 4
// baseline (484.398 us; speedup 1.0000x reference)
//
#include <hip/hip_runtime.h>

#define B_ 4
#define S_ 4096
#define E_ 2048
#define H_ 128

using f32x4 = __attribute__((ext_vector_type(4))) float;
using s16x8 = __attribute__((ext_vector_type(8))) short;
using s16x4 = __attribute__((ext_vector_type(4))) short;

// fp32 -> bf16 bits, round-to-nearest-even
__device__ __forceinline__ short f2bf(float f) {
  unsigned u = __float_as_uint(f);
  u += 0x7FFFu + ((u >> 16) & 1u);
  return (short)(u >> 16);
}

// ---------------------------------------------------------------------------
// Kernel 1: W (E x H fp32) x3 -> Wt (384 x 2048 bf16) via LDS tile transpose.
// ---------------------------------------------------------------------------
__global__ __launch_bounds__(256) void prep_weights(
    const float* __restrict__ Wq, const float* __restrict__ Wk,
    const float* __restrict__ Wv, short* __restrict__ Wt) {
  __shared__ float T[32 * 33];
  int p = blockIdx.y;
  const float* W = (p == 0) ? Wq : ((p == 1) ? Wk : Wv);
  int e0 = (blockIdx.x & 63) * 32;
  int h0 = (blockIdx.x >> 6) * 32;
  int r = threadIdx.x >> 5;
  int c = threadIdx.x & 31;
#pragma unroll
  for (int i = 0; i < 4; ++i) {
    int e = r + 8 * i;
    T[c * 33 + e] = W[(size_t)(e0 + e) * H_ + h0 + c];
  }
  __syncthreads();
#pragma unroll
  for (int i = 0; i < 4; ++i) {
    int h = r + 8 * i;
    Wt[(size_t)(p * H_ + h0 + h) * E_ + e0 + c] = f2bf(T[h * 33 + c]);
  }
}

// ---------------------------------------------------------------------------
// Kernel 2: fused QKV projection GEMM, N SPLIT IN TWO 192-col halves.
// 1024 blocks (4/CU, 16 waves/CU; v3 had 512 = 8 waves/CU, latency-bound).
// Block = 32 rows x 192 cols, BK=32, register-prefetch pipeline.
// x re-read (2nd half) hits L3 (134MB < 256MB). Q pre-scaled by 1/sqrt(H);
// V written transposed Vt[b][h][s].
// ---------------------------------------------------------------------------
__global__ __launch_bounds__(256, 4) void qkv_gemm(
    const float* __restrict__ x, const short* __restrict__ Wt,
    const float* __restrict__ bq, const float* __restrict__ bk,
    const float* __restrict__ bv,
    short* __restrict__ Q, short* __restrict__ K, short* __restrict__ Vt) {
  __shared__ __attribute__((aligned(16))) short xa[32 * 40];
  __shared__ __attribute__((aligned(16))) short wb[192 * 40];

  const int tid = threadIdx.x;
  const int wave = tid >> 6;
  const int lane = tid & 63;
  const int l15 = lane & 15;
  const int quad = lane >> 4;
  const int row0 = (blockIdx.x >> 1) * 32;
  const int nc0 = (blockIdx.x & 1) * 192;

  f32x4 acc[2][3];
#pragma unroll
  for (int mg = 0; mg < 2; ++mg)
#pragma unroll
    for (int nt = 0; nt < 3; ++nt) acc[mg][nt] = (f32x4){0.f, 0.f, 0.f, 0.f};

  const int sr = tid >> 3;          // x row 0..31
  const int sc4 = (tid & 7) * 4;    // x col 0,4..28
  const int wr = tid >> 2;          // W row base 0..63 (+64*i2)
  const int wo = (tid & 3) * 8;     // W col 0,8,16,24
  const float* xp = x + (size_t)(row0 + sr) * E_ + sc4;
  const short* wp = Wt + (size_t)(nc0 + wr) * E_ + wo;

  // prefetch tile 0
  float4 xf = *(const float4*)(xp);
  s16x8 wreg[3];
#pragma unroll
  for (int i2 = 0; i2 < 3; ++i2)
    wreg[i2] = *(const s16x8*)(wp + (size_t)(64 * i2) * E_);

  for (int it = 0; it < 64; ++it) {
    __syncthreads();
    {
      s16x4 xv;
      xv[0] = f2bf(xf.x); xv[1] = f2bf(xf.y); xv[2] = f2bf(xf.z); xv[3] = f2bf(xf.w);
      *(s16x4*)&xa[sr * 40 + sc4] = xv;
    }
#pragma unroll
    for (int i2 = 0; i2 < 3; ++i2)
      *(s16x8*)&wb[(wr + 64 * i2) * 40 + wo] = wreg[i2];
    __syncthreads();

    if (it < 63) {  // prefetch next tile, overlaps MFMAs below
      const int k0n = (it + 1) * 32;
      xf = *(const float4*)(xp + k0n);
#pragma unroll
      for (int i2 = 0; i2 < 3; ++i2)
        wreg[i2] = *(const s16x8*)(wp + (size_t)(64 * i2) * E_ + k0n);
    }

    s16x8 af[2], bfr[3];
#pragma unroll
    for (int mg = 0; mg < 2; ++mg)
      af[mg] = *(const s16x8*)&xa[(mg * 16 + l15) * 40 + quad * 8];
#pragma unroll
    for (int nt = 0; nt < 3; ++nt)
      bfr[nt] = *(const s16x8*)&wb[(wave * 48 + nt * 16 + l15) * 40 + quad * 8];
#pragma unroll
    for (int mg = 0; mg < 2; ++mg)
#pragma unroll
      for (int nt = 0; nt < 3; ++nt)
        acc[mg][nt] = __builtin_amdgcn_mfma_f32_16x16x32_bf16(
            af[mg], bfr[nt], acc[mg][nt], 0, 0, 0);
  }

  // epilogue
  const float scale = 0.08838834764831845f;  // 1/sqrt(128), folded into Q
  const int b = row0 >> 12;
  const int s_base = row0 & (S_ - 1);
#pragma unroll
  for (int nt = 0; nt < 3; ++nt) {
    int col = nc0 + wave * 48 + nt * 16 + l15;
    int p = col >> 7;
    int h = col & (H_ - 1);
    if (p == 2) {  // V -> Vt[b][h][s], packed 8B stores
      float bsv = bv[h];
#pragma unroll
      for (int mg = 0; mg < 2; ++mg) {
        int s0 = s_base + mg * 16 + quad * 4;
        s16x4 vv;
#pragma unroll
        for (int r = 0; r < 4; ++r) vv[r] = f2bf(acc[mg][nt][r] + bsv);
        *(s16x4*)&Vt[((size_t)b * H_ + h) * S_ + s0] = vv;
      }
    } else if (p == 0) {  // Q, pre-scaled
      float bsv = bq[h];
#pragma unroll
      for (int mg = 0; mg < 2; ++mg)
#pragma unroll
        for (int r = 0; r < 4; ++r) {
          int row = row0 + mg * 16 + quad * 4 + r;
          Q[(size_t)row * H_ + h] = f2bf((acc[mg][nt][r] + bsv) * scale);
        }
    } else {
      float bsv = bk[h];
#pragma unroll
      for (int mg = 0; mg < 2; ++mg)
#pragma unroll
        for (int r = 0; r < 4; ++r) {
          int row = row0 + mg * 16 + quad * 4 + r;
          K[(size_t)row * H_ + h] = f2bf(acc[mg][nt][r] + bsv);
        }
    }
  }
}

// ---------------------------------------------------------------------------
// Kernel 3: causal flash attention, 8-WAY intra-block k-split.
// Block (512 thr = 8 waves) = one 16-row q-tile; wave w does k-tiles
// w, w+8, ... with private online-softmax state; chunked LDS merge at end.
// 1024 blocks, ~36KB LDS, VGPR<=64 -> 4 blocks/CU = 32 waves/CU (8/SIMD).
// Q pre-scaled; K read [s][h], V read transposed [h][s].
// ---------------------------------------------------------------------------
__global__ __launch_bounds__(512, 8) void flash_attn(
    const short* __restrict__ Qb, const short* __restrict__ Kb,
    const short* __restrict__ Vtb, float* __restrict__ out) {
  __shared__ __attribute__((aligned(16))) short p_all[8 * 16 * 72];  // 18.4 KB
  __shared__ float Ob[8 * 16 * 33];                                  // 16.9 KB
  __shared__ float mlds[128], llds[128];

  const int tid = threadIdx.x;
  const int w = tid >> 6;
  const int lane = tid & 63;
  const int l15 = lane & 15;
  const int quad = lane >> 4;
  const int t = 255 - (blockIdx.x >> 2);  // heavy q-tiles first
  const int b = blockIdx.x & 3;
  const int q0 = t * 16;
  const size_t bo = (size_t)b * S_ * H_;
  const short* Vb = Vtb + (size_t)b * H_ * S_;  // [h][s]
  const float L2E = 1.4426950408889634f;
  const int nk = (t >> 2) + 1;  // 64-key tiles covering causal range

  short* p_lds = &p_all[w * (16 * 72)];

  s16x8 aq[4];
#pragma unroll
  for (int kt = 0; kt < 4; ++kt)
    aq[kt] = *(const s16x8*)(Qb + bo + (size_t)(q0 + l15) * H_ + kt * 32 + quad * 8);

  f32x4 oacc[8];
#pragma unroll
  for (int nt = 0; nt < 8; ++nt) oacc[nt] = (f32x4){0.f, 0.f, 0.f, 0.f};
  float m_r[4], l_r[4];
#pragma unroll
  for (int r = 0; r < 4; ++r) { m_r[r] = -3.0e38f; l_r[r] = 0.f; }

  for (int i = w; i < nk; i += 8) {
    const int kb = i * 64;
    // scores S = Q @ K^T (16 x 64), Q pre-scaled
    f32x4 sc[4];
#pragma unroll
    for (int nt = 0; nt < 4; ++nt) {
      f32x4 a = (f32x4){0.f, 0.f, 0.f, 0.f};
      const short* kp = Kb + bo + (size_t)(kb + nt * 16 + l15) * H_ + quad * 8;
#pragma unroll
      for (int kt = 0; kt < 4; ++kt)
        a = __builtin_amdgcn_mfma_f32_16x16x32_bf16(
            aq[kt], *(const s16x8*)(kp + kt * 32), a, 0, 0, 0);
      sc[nt] = a;
    }
    if (i == nk - 1) {  // diagonal k-tile: causal mask
      const int qloc = (t & 3) * 16 + quad * 4;
#pragma unroll
      for (int nt = 0; nt < 4; ++nt)
#pragma unroll
        for (int r = 0; r < 4; ++r)
          if (nt * 16 + l15 > qloc + r) sc[nt][r] = -3.0e38f;
    }
    // row max across the quad's 16 lanes
    float vm[4];
#pragma unroll
    for (int r = 0; r < 4; ++r)
      vm[r] = fmaxf(fmaxf(sc[0][r], sc[1][r]), fmaxf(sc[2][r], sc[3][r]));
#pragma unroll
    for (int off = 1; off < 16; off <<= 1)
#pragma unroll
      for (int r = 0; r < 4; ++r) vm[r] = fmaxf(vm[r], __shfl_xor(vm[r], off));

    float al[4];
#pragma unroll
    for (int r = 0; r < 4; ++r) {
      float mn = fmaxf(m_r[r], vm[r]);
      al[r] = exp2f((m_r[r] - mn) * L2E);
      m_r[r] = mn;
    }
    float rs[4] = {0.f, 0.f, 0.f, 0.f};
#pragma unroll
    for (int nt = 0; nt < 4; ++nt)
#pragma unroll
      for (int r = 0; r < 4; ++r) {
        float pv = exp2f((sc[nt][r] - m_r[r]) * L2E);
        sc[nt][r] = pv;
        rs[r] += pv;
      }
#pragma unroll
    for (int off = 1; off < 16; off <<= 1)
#pragma unroll
      for (int r = 0; r < 4; ++r) rs[r] += __shfl_xor(rs[r], off);
#pragma unroll
    for (int r = 0; r < 4; ++r) l_r[r] = l_r[r] * al[r] + rs[r];
#pragma unroll
    for (int nt = 0; nt < 8; ++nt)
#pragma unroll
      for (int r = 0; r < 4; ++r) oacc[nt][r] *= al[r];

    // P (C-layout) -> per-wave LDS -> A-layout bf16 (wave-local sync only)
    __asm__ volatile("s_waitcnt lgkmcnt(0)" ::: "memory");
#pragma unroll
    for (int nt = 0; nt < 4; ++nt)
#pragma unroll
      for (int r = 0; r < 4; ++r)
        p_lds[(quad * 4 + r) * 72 + nt * 16 + l15] = f2bf(sc[nt][r]);
    __asm__ volatile("s_waitcnt lgkmcnt(0)" ::: "memory");

    s16x8 ap[2];
#pragma unroll
    for (int kt2 = 0; kt2 < 2; ++kt2)
      ap[kt2] = *(const s16x8*)&p_lds[l15 * 72 + kt2 * 32 + quad * 8];

    // O += P @ V from Vt[h][s]
#pragma unroll
    for (int nt = 0; nt < 8; ++nt) {
      const short* vp = Vb + (size_t)(nt * 16 + l15) * S_ + kb + quad * 8;
#pragma unroll
      for (int kt2 = 0; kt2 < 2; ++kt2)
        oacc[nt] = __builtin_amdgcn_mfma_f32_16x16x32_bf16(
            ap[kt2], *(const s16x8*)(vp + kt2 * 32), oacc[nt], 0, 0, 0);
    }
  }

  // ---- 8-way cross-wave merge, chunked 32 cols at a time ----
  if (l15 == 0) {
#pragma unroll
    for (int r = 0; r < 4; ++r) {
      mlds[w * 16 + quad * 4 + r] = m_r[r];
      llds[w * 16 + quad * 4 + r] = l_r[r];
    }
  }
  __syncthreads();

  const int row = tid >> 5;   // 0..15
  const int col = tid & 31;   // 0..31
  float mw[8], ms;
#pragma unroll
  for (int w2 = 0; w2 < 8; ++w2) mw[w2] = mlds[w2 * 16 + row];
  ms = mw[0];
#pragma unroll
  for (int w2 = 1; w2 < 8; ++w2) ms = fmaxf(ms, mw[w2]);
  float fw[8], lf = 0.f;
#pragma unroll
  for (int w2 = 0; w2 < 8; ++w2) {
    fw[w2] = exp2f((mw[w2] - ms) * L2E);
    lf += fw[w2] * llds[w2 * 16 + row];
  }
  const float invl = 1.0f / lf;

#pragma unroll
  for (int c = 0; c < 4; ++c) {
    // each wave writes its cols [c*32, c*32+32) = acc tiles nt=2c, 2c+1
#pragma unroll
    for (int j = 0; j < 2; ++j) {
      int nt = 2 * c + j;
#pragma unroll
      for (int r = 0; r < 4; ++r)
        Ob[(w * 16 + quad * 4 + r) * 33 + j * 16 + l15] = oacc[nt][r];
    }
    __syncthreads();
    float o = 0.f;
#pragma unroll
    for (int w2 = 0; w2 < 8; ++w2) o += fw[w2] * Ob[(w2 * 16 + row) * 33 + col];
    out[bo + (size_t)(q0 + row) * H_ + c * 32 + col] = o * invl;
    __syncthreads();  // buffer reused next chunk
  }
}

// ---------------------------------------------------------------------------
extern "C" void kernel_launch(void* const* d_in, const int* in_sizes, int n_in,
                              void* d_out, int out_size, void* d_ws, size_t ws_size,
                              hipStream_t stream) {
  const float* x  = (const float*)d_in[0];
  const float* Wq = (const float*)d_in[1];
  const float* bq = (const float*)d_in[2];
  const float* Wk = (const float*)d_in[3];
  const float* bk = (const float*)d_in[4];
  const float* Wv = (const float*)d_in[5];
  const float* bv = (const float*)d_in[6];

  // ws layout: Wt (384*2048 bf16) | Q | K | Vt (each B*S*H bf16) ~= 13.5 MB
  short* Wt = (short*)d_ws;
  short* Q  = Wt + (size_t)384 * E_;
  short* K  = Q + (size_t)B_ * S_ * H_;
  short* Vt = K + (size_t)B_ * S_ * H_;
  float* out = (float*)d_out;

  hipLaunchKernelGGL(prep_weights, dim3(64 * 4, 3), dim3(256), 0, stream,
                     Wq, Wk, Wv, Wt);
  hipLaunchKernelGGL(qkv_gemm, dim3((B_ * S_) / 32 * 2), dim3(256), 0, stream,
                     x, Wt, bq, bk, bv, Q, K, Vt);
  hipLaunchKernelGGL(flash_attn, dim3((S_ / 16) * B_), dim3(512), 0, stream,
                     Q, K, Vt, out);
}

// Round 5
// 474.411 us; speedup vs baseline: 1.0211x; 1.0211x over previous
//
#include <hip/hip_runtime.h>

#define B_ 4
#define S_ 4096
#define E_ 2048
#define H_ 128

using f32x4 = __attribute__((ext_vector_type(4))) float;
using s16x8 = __attribute__((ext_vector_type(8))) short;
using s16x4 = __attribute__((ext_vector_type(4))) short;

// fp32 -> bf16 bits, round-to-nearest-even
__device__ __forceinline__ short f2bf(float f) {
  unsigned u = __float_as_uint(f);
  u += 0x7FFFu + ((u >> 16) & 1u);
  return (short)(u >> 16);
}

// ---------------------------------------------------------------------------
// Kernel 1: W (E x H fp32) x3 -> Wt (384 x 2048 bf16) via LDS tile transpose.
// ---------------------------------------------------------------------------
__global__ __launch_bounds__(256) void prep_weights(
    const float* __restrict__ Wq, const float* __restrict__ Wk,
    const float* __restrict__ Wv, short* __restrict__ Wt) {
  __shared__ float T[32 * 33];
  int p = blockIdx.y;
  const float* W = (p == 0) ? Wq : ((p == 1) ? Wk : Wv);
  int e0 = (blockIdx.x & 63) * 32;
  int h0 = (blockIdx.x >> 6) * 32;
  int r = threadIdx.x >> 5;
  int c = threadIdx.x & 31;
#pragma unroll
  for (int i = 0; i < 4; ++i) {
    int e = r + 8 * i;
    T[c * 33 + e] = W[(size_t)(e0 + e) * H_ + h0 + c];
  }
  __syncthreads();
#pragma unroll
  for (int i = 0; i < 4; ++i) {
    int h = r + 8 * i;
    Wt[(size_t)(p * H_ + h0 + h) * E_ + e0 + c] = f2bf(T[h * 33 + c]);
  }
}

// ---------------------------------------------------------------------------
// Kernel 2: fused QKV projection GEMM (UNCHANGED from R4 — isolating the
// flash fix this round so gemm's counters finally surface in the top-5).
// ---------------------------------------------------------------------------
__global__ __launch_bounds__(256, 4) void qkv_gemm(
    const float* __restrict__ x, const short* __restrict__ Wt,
    const float* __restrict__ bq, const float* __restrict__ bk,
    const float* __restrict__ bv,
    short* __restrict__ Q, short* __restrict__ K, short* __restrict__ Vt) {
  __shared__ __attribute__((aligned(16))) short xa[32 * 40];
  __shared__ __attribute__((aligned(16))) short wb[192 * 40];

  const int tid = threadIdx.x;
  const int wave = tid >> 6;
  const int lane = tid & 63;
  const int l15 = lane & 15;
  const int quad = lane >> 4;
  const int row0 = (blockIdx.x >> 1) * 32;
  const int nc0 = (blockIdx.x & 1) * 192;

  f32x4 acc[2][3];
#pragma unroll
  for (int mg = 0; mg < 2; ++mg)
#pragma unroll
    for (int nt = 0; nt < 3; ++nt) acc[mg][nt] = (f32x4){0.f, 0.f, 0.f, 0.f};

  const int sr = tid >> 3;
  const int sc4 = (tid & 7) * 4;
  const int wr = tid >> 2;
  const int wo = (tid & 3) * 8;
  const float* xp = x + (size_t)(row0 + sr) * E_ + sc4;
  const short* wp = Wt + (size_t)(nc0 + wr) * E_ + wo;

  float4 xf = *(const float4*)(xp);
  s16x8 wreg[3];
#pragma unroll
  for (int i2 = 0; i2 < 3; ++i2)
    wreg[i2] = *(const s16x8*)(wp + (size_t)(64 * i2) * E_);

  for (int it = 0; it < 64; ++it) {
    __syncthreads();
    {
      s16x4 xv;
      xv[0] = f2bf(xf.x); xv[1] = f2bf(xf.y); xv[2] = f2bf(xf.z); xv[3] = f2bf(xf.w);
      *(s16x4*)&xa[sr * 40 + sc4] = xv;
    }
#pragma unroll
    for (int i2 = 0; i2 < 3; ++i2)
      *(s16x8*)&wb[(wr + 64 * i2) * 40 + wo] = wreg[i2];
    __syncthreads();

    if (it < 63) {
      const int k0n = (it + 1) * 32;
      xf = *(const float4*)(xp + k0n);
#pragma unroll
      for (int i2 = 0; i2 < 3; ++i2)
        wreg[i2] = *(const s16x8*)(wp + (size_t)(64 * i2) * E_ + k0n);
    }

    s16x8 af[2], bfr[3];
#pragma unroll
    for (int mg = 0; mg < 2; ++mg)
      af[mg] = *(const s16x8*)&xa[(mg * 16 + l15) * 40 + quad * 8];
#pragma unroll
    for (int nt = 0; nt < 3; ++nt)
      bfr[nt] = *(const s16x8*)&wb[(wave * 48 + nt * 16 + l15) * 40 + quad * 8];
#pragma unroll
    for (int mg = 0; mg < 2; ++mg)
#pragma unroll
      for (int nt = 0; nt < 3; ++nt)
        acc[mg][nt] = __builtin_amdgcn_mfma_f32_16x16x32_bf16(
            af[mg], bfr[nt], acc[mg][nt], 0, 0, 0);
  }

  const float scale = 0.08838834764831845f;  // 1/sqrt(128), folded into Q
  const int b = row0 >> 12;
  const int s_base = row0 & (S_ - 1);
#pragma unroll
  for (int nt = 0; nt < 3; ++nt) {
    int col = nc0 + wave * 48 + nt * 16 + l15;
    int p = col >> 7;
    int h = col & (H_ - 1);
    if (p == 2) {
      float bsv = bv[h];
#pragma unroll
      for (int mg = 0; mg < 2; ++mg) {
        int s0 = s_base + mg * 16 + quad * 4;
        s16x4 vv;
#pragma unroll
        for (int r = 0; r < 4; ++r) vv[r] = f2bf(acc[mg][nt][r] + bsv);
        *(s16x4*)&Vt[((size_t)b * H_ + h) * S_ + s0] = vv;
      }
    } else if (p == 0) {
      float bsv = bq[h];
#pragma unroll
      for (int mg = 0; mg < 2; ++mg)
#pragma unroll
        for (int r = 0; r < 4; ++r) {
          int row = row0 + mg * 16 + quad * 4 + r;
          Q[(size_t)row * H_ + h] = f2bf((acc[mg][nt][r] + bsv) * scale);
        }
    } else {
      float bsv = bk[h];
#pragma unroll
      for (int mg = 0; mg < 2; ++mg)
#pragma unroll
        for (int r = 0; r < 4; ++r) {
          int row = row0 + mg * 16 + quad * 4 + r;
          K[(size_t)row * H_ + h] = f2bf(acc[mg][nt][r] + bsv);
        }
    }
  }
}

// ---------------------------------------------------------------------------
// Kernel 3: causal flash attention, 4-way k-split (R3-proven codegen, 64 VGPR)
// with LDS trimmed to ~17.8 KB via chunked merge -> 8 blocks/CU = 32 waves/CU
// (R3 was LDS-capped at 4 blocks/CU = 16 waves). Gentle __launch_bounds__
// (256,6): budget 85 regs, no spill pressure (R4's (512,8) forced VGPR=32 and
// spilled ~500 MB/dispatch of scratch to HBM).
// ---------------------------------------------------------------------------
__global__ __launch_bounds__(256, 6) void flash_attn(
    const short* __restrict__ Qb, const short* __restrict__ Kb,
    const short* __restrict__ Vtb, float* __restrict__ out) {
  __shared__ __attribute__((aligned(16))) short p_all[4 * 16 * 72];  // 9216 B
  __shared__ float Ob[4 * 16 * 33];                                  // 8448 B
  __shared__ float mlds[64], llds[64];                               //  512 B

  const int tid = threadIdx.x;
  const int w = tid >> 6;
  const int lane = tid & 63;
  const int l15 = lane & 15;
  const int quad = lane >> 4;
  const int t = 255 - (blockIdx.x >> 2);  // heavy q-tiles first
  const int b = blockIdx.x & 3;
  const int q0 = t * 16;
  const size_t bo = (size_t)b * S_ * H_;
  const short* Vb = Vtb + (size_t)b * H_ * S_;  // [h][s]
  const float L2E = 1.4426950408889634f;
  const int nk = (t >> 2) + 1;  // 64-key tiles covering causal range

  short* p_lds = &p_all[w * (16 * 72)];

  s16x8 aq[4];
#pragma unroll
  for (int kt = 0; kt < 4; ++kt)
    aq[kt] = *(const s16x8*)(Qb + bo + (size_t)(q0 + l15) * H_ + kt * 32 + quad * 8);

  f32x4 oacc[8];
#pragma unroll
  for (int nt = 0; nt < 8; ++nt) oacc[nt] = (f32x4){0.f, 0.f, 0.f, 0.f};
  float m_r[4], l_r[4];
#pragma unroll
  for (int r = 0; r < 4; ++r) { m_r[r] = -3.0e38f; l_r[r] = 0.f; }

  for (int i = w; i < nk; i += 4) {
    const int kb = i * 64;
    // scores S = Q @ K^T (16 x 64), Q pre-scaled
    f32x4 sc[4];
#pragma unroll
    for (int nt = 0; nt < 4; ++nt) {
      f32x4 a = (f32x4){0.f, 0.f, 0.f, 0.f};
      const short* kp = Kb + bo + (size_t)(kb + nt * 16 + l15) * H_ + quad * 8;
#pragma unroll
      for (int kt = 0; kt < 4; ++kt)
        a = __builtin_amdgcn_mfma_f32_16x16x32_bf16(
            aq[kt], *(const s16x8*)(kp + kt * 32), a, 0, 0, 0);
      sc[nt] = a;
    }
    if (i == nk - 1) {  // diagonal k-tile: causal mask
      const int qloc = (t & 3) * 16 + quad * 4;
#pragma unroll
      for (int nt = 0; nt < 4; ++nt)
#pragma unroll
        for (int r = 0; r < 4; ++r)
          if (nt * 16 + l15 > qloc + r) sc[nt][r] = -3.0e38f;
    }
    // row max across the quad's 16 lanes
    float vm[4];
#pragma unroll
    for (int r = 0; r < 4; ++r)
      vm[r] = fmaxf(fmaxf(sc[0][r], sc[1][r]), fmaxf(sc[2][r], sc[3][r]));
#pragma unroll
    for (int off = 1; off < 16; off <<= 1)
#pragma unroll
      for (int r = 0; r < 4; ++r) vm[r] = fmaxf(vm[r], __shfl_xor(vm[r], off));

    float al[4];
#pragma unroll
    for (int r = 0; r < 4; ++r) {
      float mn = fmaxf(m_r[r], vm[r]);
      al[r] = exp2f((m_r[r] - mn) * L2E);
      m_r[r] = mn;
    }
    float rs[4] = {0.f, 0.f, 0.f, 0.f};
#pragma unroll
    for (int nt = 0; nt < 4; ++nt)
#pragma unroll
      for (int r = 0; r < 4; ++r) {
        float pv = exp2f((sc[nt][r] - m_r[r]) * L2E);
        sc[nt][r] = pv;
        rs[r] += pv;
      }
#pragma unroll
    for (int off = 1; off < 16; off <<= 1)
#pragma unroll
      for (int r = 0; r < 4; ++r) rs[r] += __shfl_xor(rs[r], off);
#pragma unroll
    for (int r = 0; r < 4; ++r) l_r[r] = l_r[r] * al[r] + rs[r];
#pragma unroll
    for (int nt = 0; nt < 8; ++nt)
#pragma unroll
      for (int r = 0; r < 4; ++r) oacc[nt][r] *= al[r];

    // P (C-layout) -> per-wave LDS -> A-layout bf16 (wave-local sync only)
    __asm__ volatile("s_waitcnt lgkmcnt(0)" ::: "memory");
#pragma unroll
    for (int nt = 0; nt < 4; ++nt)
#pragma unroll
      for (int r = 0; r < 4; ++r)
        p_lds[(quad * 4 + r) * 72 + nt * 16 + l15] = f2bf(sc[nt][r]);
    __asm__ volatile("s_waitcnt lgkmcnt(0)" ::: "memory");

    s16x8 ap[2];
#pragma unroll
    for (int kt2 = 0; kt2 < 2; ++kt2)
      ap[kt2] = *(const s16x8*)&p_lds[l15 * 72 + kt2 * 32 + quad * 8];

    // O += P @ V from Vt[h][s]
#pragma unroll
    for (int nt = 0; nt < 8; ++nt) {
      const short* vp = Vb + (size_t)(nt * 16 + l15) * S_ + kb + quad * 8;
#pragma unroll
      for (int kt2 = 0; kt2 < 2; ++kt2)
        oacc[nt] = __builtin_amdgcn_mfma_f32_16x16x32_bf16(
            ap[kt2], *(const s16x8*)(vp + kt2 * 32), oacc[nt], 0, 0, 0);
    }
  }

  // ---- 4-way cross-wave merge, chunked 32 cols at a time (small LDS) ----
  if (l15 == 0) {
#pragma unroll
    for (int r = 0; r < 4; ++r) {
      mlds[w * 16 + quad * 4 + r] = m_r[r];
      llds[w * 16 + quad * 4 + r] = l_r[r];
    }
  }
  __syncthreads();

  const int row = tid >> 4;        // 0..15
  const int c2 = (tid & 15) * 2;   // 0,2,..30 within a 32-col chunk
  float mw[4];
#pragma unroll
  for (int w2 = 0; w2 < 4; ++w2) mw[w2] = mlds[w2 * 16 + row];
  float ms = fmaxf(fmaxf(mw[0], mw[1]), fmaxf(mw[2], mw[3]));
  float fw[4], lf = 0.f;
#pragma unroll
  for (int w2 = 0; w2 < 4; ++w2) {
    fw[w2] = exp2f((mw[w2] - ms) * L2E);
    lf += fw[w2] * llds[w2 * 16 + row];
  }
  const float invl = 1.0f / lf;

#pragma unroll
  for (int c = 0; c < 4; ++c) {
    // each wave writes its cols [c*32, c*32+32) = acc tiles nt=2c, 2c+1
#pragma unroll
    for (int j = 0; j < 2; ++j) {
      int nt = 2 * c + j;
#pragma unroll
      for (int r = 0; r < 4; ++r)
        Ob[(w * 16 + quad * 4 + r) * 33 + j * 16 + l15] = oacc[nt][r];
    }
    __syncthreads();
    float o0 = 0.f, o1 = 0.f;
#pragma unroll
    for (int w2 = 0; w2 < 4; ++w2) {
      o0 += fw[w2] * Ob[(w2 * 16 + row) * 33 + c2];
      o1 += fw[w2] * Ob[(w2 * 16 + row) * 33 + c2 + 1];
    }
    float* op = out + bo + (size_t)(q0 + row) * H_ + c * 32 + c2;
    op[0] = o0 * invl;
    op[1] = o1 * invl;
    __syncthreads();  // buffer reused next chunk
  }
}

// ---------------------------------------------------------------------------
extern "C" void kernel_launch(void* const* d_in, const int* in_sizes, int n_in,
                              void* d_out, int out_size, void* d_ws, size_t ws_size,
                              hipStream_t stream) {
  const float* x  = (const float*)d_in[0];
  const float* Wq = (const float*)d_in[1];
  const float* bq = (const float*)d_in[2];
  const float* Wk = (const float*)d_in[3];
  const float* bk = (const float*)d_in[4];
  const float* Wv = (const float*)d_in[5];
  const float* bv = (const float*)d_in[6];

  // ws layout: Wt (384*2048 bf16) | Q | K | Vt (each B*S*H bf16) ~= 13.5 MB
  short* Wt = (short*)d_ws;
  short* Q  = Wt + (size_t)384 * E_;
  short* K  = Q + (size_t)B_ * S_ * H_;
  short* Vt = K + (size_t)B_ * S_ * H_;
  float* out = (float*)d_out;

  hipLaunchKernelGGL(prep_weights, dim3(64 * 4, 3), dim3(256), 0, stream,
                     Wq, Wk, Wv, Wt);
  hipLaunchKernelGGL(qkv_gemm, dim3((B_ * S_) / 32 * 2), dim3(256), 0, stream,
                     x, Wt, bq, bk, bv, Q, K, Vt);
  hipLaunchKernelGGL(flash_attn, dim3((S_ / 16) * B_), dim3(256), 0, stream,
                     Q, K, Vt, out);
}

// Round 6
// 394.795 us; speedup vs baseline: 1.2270x; 1.2017x over previous
//
#include <hip/hip_runtime.h>

#define B_ 4
#define S_ 4096
#define E_ 2048
#define H_ 128

using f32x4 = __attribute__((ext_vector_type(4))) float;
using s16x8 = __attribute__((ext_vector_type(8))) short;
using s16x4 = __attribute__((ext_vector_type(4))) short;

// fp32 -> bf16 bits, round-to-nearest-even
__device__ __forceinline__ short f2bf(float f) {
  unsigned u = __float_as_uint(f);
  u += 0x7FFFu + ((u >> 16) & 1u);
  return (short)(u >> 16);
}

// ---------------------------------------------------------------------------
// Kernel 1: W (E x H fp32) x3 -> Wt (384 x 2048 bf16) via LDS tile transpose.
// ---------------------------------------------------------------------------
__global__ __launch_bounds__(256) void prep_weights(
    const float* __restrict__ Wq, const float* __restrict__ Wk,
    const float* __restrict__ Wv, short* __restrict__ Wt) {
  __shared__ float T[32 * 33];
  int p = blockIdx.y;
  const float* W = (p == 0) ? Wq : ((p == 1) ? Wk : Wv);
  int e0 = (blockIdx.x & 63) * 32;
  int h0 = (blockIdx.x >> 6) * 32;
  int r = threadIdx.x >> 5;
  int c = threadIdx.x & 31;
#pragma unroll
  for (int i = 0; i < 4; ++i) {
    int e = r + 8 * i;
    T[c * 33 + e] = W[(size_t)(e0 + e) * H_ + h0 + c];
  }
  __syncthreads();
#pragma unroll
  for (int i = 0; i < 4; ++i) {
    int h = r + 8 * i;
    Wt[(size_t)(p * H_ + h0 + h) * E_ + e0 + c] = f2bf(T[h * 33 + c]);
  }
}

// ---------------------------------------------------------------------------
// Kernel 2: fused QKV projection GEMM, BK=64 (was 32): 32 iters, half the
// barriers, 12 MFMAs/wave/iter, prefetch covers a full 64-k-slab of latency.
// Block = 32 rows x 192 cols; 1024 blocks. NO min-waves hint (spill hazard:
// R4 (512,8)->VGPR32, R5 (256,6)->VGPR40 both spilled ~100s of MB to scratch).
// Q pre-scaled by 1/sqrt(H); V written transposed Vt[b][h][s].
// ---------------------------------------------------------------------------
__global__ __launch_bounds__(256) void qkv_gemm(
    const float* __restrict__ x, const short* __restrict__ Wt,
    const float* __restrict__ bq, const float* __restrict__ bk,
    const float* __restrict__ bv,
    short* __restrict__ Q, short* __restrict__ K, short* __restrict__ Vt) {
  __shared__ __attribute__((aligned(16))) short xa[32 * 72];   //  4.6 KB
  __shared__ __attribute__((aligned(16))) short wb[192 * 72];  // 27.6 KB

  const int tid = threadIdx.x;
  const int wave = tid >> 6;
  const int lane = tid & 63;
  const int l15 = lane & 15;
  const int quad = lane >> 4;
  const int row0 = (blockIdx.x >> 1) * 32;
  const int nc0 = (blockIdx.x & 1) * 192;

  f32x4 acc[2][3];
#pragma unroll
  for (int mg = 0; mg < 2; ++mg)
#pragma unroll
    for (int nt = 0; nt < 3; ++nt) acc[mg][nt] = (f32x4){0.f, 0.f, 0.f, 0.f};

  // staging coords (BK=64)
  const int sr = tid >> 3;          // x row 0..31
  const int sc8 = (tid & 7) * 8;    // x col 0,8..56
  const int wr = tid >> 2;          // W row base 0..63 (+64*j)
  const int wo = (tid & 3) * 16;    // W col 0,16,32,48
  const float* xp = x + (size_t)(row0 + sr) * E_ + sc8;
  const short* wp = Wt + (size_t)(nc0 + wr) * E_ + wo;

  // prefetch slab 0
  float4 xf0 = *(const float4*)(xp);
  float4 xf1 = *(const float4*)(xp + 4);
  s16x8 wreg[6];
#pragma unroll
  for (int j = 0; j < 3; ++j) {
    wreg[2 * j]     = *(const s16x8*)(wp + (size_t)(64 * j) * E_);
    wreg[2 * j + 1] = *(const s16x8*)(wp + (size_t)(64 * j) * E_ + 8);
  }

  for (int it = 0; it < 32; ++it) {
    __syncthreads();
    {
      s16x8 xv;
      xv[0] = f2bf(xf0.x); xv[1] = f2bf(xf0.y); xv[2] = f2bf(xf0.z); xv[3] = f2bf(xf0.w);
      xv[4] = f2bf(xf1.x); xv[5] = f2bf(xf1.y); xv[6] = f2bf(xf1.z); xv[7] = f2bf(xf1.w);
      *(s16x8*)&xa[sr * 72 + sc8] = xv;
    }
#pragma unroll
    for (int j = 0; j < 3; ++j) {
      *(s16x8*)&wb[(wr + 64 * j) * 72 + wo] = wreg[2 * j];
      *(s16x8*)&wb[(wr + 64 * j) * 72 + wo + 8] = wreg[2 * j + 1];
    }
    __syncthreads();

    if (it < 31) {  // prefetch next 64-k slab, overlaps MFMAs below
      const int k0n = (it + 1) * 64;
      xf0 = *(const float4*)(xp + k0n);
      xf1 = *(const float4*)(xp + k0n + 4);
#pragma unroll
      for (int j = 0; j < 3; ++j) {
        wreg[2 * j]     = *(const s16x8*)(wp + (size_t)(64 * j) * E_ + k0n);
        wreg[2 * j + 1] = *(const s16x8*)(wp + (size_t)(64 * j) * E_ + k0n + 8);
      }
    }

#pragma unroll
    for (int kc = 0; kc < 2; ++kc) {  // two 32-k chunks of the slab
      const int ko = kc * 32 + quad * 8;
      s16x8 af[2], bfr[3];
#pragma unroll
      for (int mg = 0; mg < 2; ++mg)
        af[mg] = *(const s16x8*)&xa[(mg * 16 + l15) * 72 + ko];
#pragma unroll
      for (int nt = 0; nt < 3; ++nt)
        bfr[nt] = *(const s16x8*)&wb[(wave * 48 + nt * 16 + l15) * 72 + ko];
#pragma unroll
      for (int mg = 0; mg < 2; ++mg)
#pragma unroll
        for (int nt = 0; nt < 3; ++nt)
          acc[mg][nt] = __builtin_amdgcn_mfma_f32_16x16x32_bf16(
              af[mg], bfr[nt], acc[mg][nt], 0, 0, 0);
    }
  }

  const float scale = 0.08838834764831845f;  // 1/sqrt(128), folded into Q
  const int b = row0 >> 12;
  const int s_base = row0 & (S_ - 1);
#pragma unroll
  for (int nt = 0; nt < 3; ++nt) {
    int col = nc0 + wave * 48 + nt * 16 + l15;
    int p = col >> 7;
    int h = col & (H_ - 1);
    if (p == 2) {
      float bsv = bv[h];
#pragma unroll
      for (int mg = 0; mg < 2; ++mg) {
        int s0 = s_base + mg * 16 + quad * 4;
        s16x4 vv;
#pragma unroll
        for (int r = 0; r < 4; ++r) vv[r] = f2bf(acc[mg][nt][r] + bsv);
        *(s16x4*)&Vt[((size_t)b * H_ + h) * S_ + s0] = vv;
      }
    } else if (p == 0) {
      float bsv = bq[h];
#pragma unroll
      for (int mg = 0; mg < 2; ++mg)
#pragma unroll
        for (int r = 0; r < 4; ++r) {
          int row = row0 + mg * 16 + quad * 4 + r;
          Q[(size_t)row * H_ + h] = f2bf((acc[mg][nt][r] + bsv) * scale);
        }
    } else {
      float bsv = bk[h];
#pragma unroll
      for (int mg = 0; mg < 2; ++mg)
#pragma unroll
        for (int r = 0; r < 4; ++r) {
          int row = row0 + mg * 16 + quad * 4 + r;
          K[(size_t)row * H_ + h] = f2bf(acc[mg][nt][r] + bsv);
        }
    }
  }
}

// ---------------------------------------------------------------------------
// Kernel 3: causal flash attention, 4-way k-split, 18.4 KB LDS (chunked
// merge). PLAIN __launch_bounds__(256): R3 proved natural allocation = 64
// VGPR / no spill; min-waves hints (R4/R5) forced VGPR 32/40 + scratch
// spills. 64 VGPR allows 8 waves/SIMD; LDS allows 8 blocks/CU -> 32 waves/CU.
// ---------------------------------------------------------------------------
__global__ __launch_bounds__(256) void flash_attn(
    const short* __restrict__ Qb, const short* __restrict__ Kb,
    const short* __restrict__ Vtb, float* __restrict__ out) {
  __shared__ __attribute__((aligned(16))) short p_all[4 * 16 * 72];  // 9216 B
  __shared__ float Ob[4 * 16 * 33];                                  // 8448 B
  __shared__ float mlds[64], llds[64];                               //  512 B

  const int tid = threadIdx.x;
  const int w = tid >> 6;
  const int lane = tid & 63;
  const int l15 = lane & 15;
  const int quad = lane >> 4;
  const int t = 255 - (blockIdx.x >> 2);  // heavy q-tiles first
  const int b = blockIdx.x & 3;
  const int q0 = t * 16;
  const size_t bo = (size_t)b * S_ * H_;
  const short* Vb = Vtb + (size_t)b * H_ * S_;  // [h][s]
  const float L2E = 1.4426950408889634f;
  const int nk = (t >> 2) + 1;  // 64-key tiles covering causal range

  short* p_lds = &p_all[w * (16 * 72)];

  s16x8 aq[4];
#pragma unroll
  for (int kt = 0; kt < 4; ++kt)
    aq[kt] = *(const s16x8*)(Qb + bo + (size_t)(q0 + l15) * H_ + kt * 32 + quad * 8);

  f32x4 oacc[8];
#pragma unroll
  for (int nt = 0; nt < 8; ++nt) oacc[nt] = (f32x4){0.f, 0.f, 0.f, 0.f};
  float m_r[4], l_r[4];
#pragma unroll
  for (int r = 0; r < 4; ++r) { m_r[r] = -3.0e38f; l_r[r] = 0.f; }

  for (int i = w; i < nk; i += 4) {
    const int kb = i * 64;
    // scores S = Q @ K^T (16 x 64), Q pre-scaled
    f32x4 sc[4];
#pragma unroll
    for (int nt = 0; nt < 4; ++nt) {
      f32x4 a = (f32x4){0.f, 0.f, 0.f, 0.f};
      const short* kp = Kb + bo + (size_t)(kb + nt * 16 + l15) * H_ + quad * 8;
#pragma unroll
      for (int kt = 0; kt < 4; ++kt)
        a = __builtin_amdgcn_mfma_f32_16x16x32_bf16(
            aq[kt], *(const s16x8*)(kp + kt * 32), a, 0, 0, 0);
      sc[nt] = a;
    }
    if (i == nk - 1) {  // diagonal k-tile: causal mask
      const int qloc = (t & 3) * 16 + quad * 4;
#pragma unroll
      for (int nt = 0; nt < 4; ++nt)
#pragma unroll
        for (int r = 0; r < 4; ++r)
          if (nt * 16 + l15 > qloc + r) sc[nt][r] = -3.0e38f;
    }
    // row max across the quad's 16 lanes
    float vm[4];
#pragma unroll
    for (int r = 0; r < 4; ++r)
      vm[r] = fmaxf(fmaxf(sc[0][r], sc[1][r]), fmaxf(sc[2][r], sc[3][r]));
#pragma unroll
    for (int off = 1; off < 16; off <<= 1)
#pragma unroll
      for (int r = 0; r < 4; ++r) vm[r] = fmaxf(vm[r], __shfl_xor(vm[r], off));

    float al[4];
#pragma unroll
    for (int r = 0; r < 4; ++r) {
      float mn = fmaxf(m_r[r], vm[r]);
      al[r] = exp2f((m_r[r] - mn) * L2E);
      m_r[r] = mn;
    }
    float rs[4] = {0.f, 0.f, 0.f, 0.f};
#pragma unroll
    for (int nt = 0; nt < 4; ++nt)
#pragma unroll
      for (int r = 0; r < 4; ++r) {
        float pv = exp2f((sc[nt][r] - m_r[r]) * L2E);
        sc[nt][r] = pv;
        rs[r] += pv;
      }
#pragma unroll
    for (int off = 1; off < 16; off <<= 1)
#pragma unroll
      for (int r = 0; r < 4; ++r) rs[r] += __shfl_xor(rs[r], off);
#pragma unroll
    for (int r = 0; r < 4; ++r) l_r[r] = l_r[r] * al[r] + rs[r];
#pragma unroll
    for (int nt = 0; nt < 8; ++nt)
#pragma unroll
      for (int r = 0; r < 4; ++r) oacc[nt][r] *= al[r];

    // P (C-layout) -> per-wave LDS -> A-layout bf16 (wave-local sync only)
    __asm__ volatile("s_waitcnt lgkmcnt(0)" ::: "memory");
#pragma unroll
    for (int nt = 0; nt < 4; ++nt)
#pragma unroll
      for (int r = 0; r < 4; ++r)
        p_lds[(quad * 4 + r) * 72 + nt * 16 + l15] = f2bf(sc[nt][r]);
    __asm__ volatile("s_waitcnt lgkmcnt(0)" ::: "memory");

    s16x8 ap[2];
#pragma unroll
    for (int kt2 = 0; kt2 < 2; ++kt2)
      ap[kt2] = *(const s16x8*)&p_lds[l15 * 72 + kt2 * 32 + quad * 8];

    // O += P @ V from Vt[h][s]
#pragma unroll
    for (int nt = 0; nt < 8; ++nt) {
      const short* vp = Vb + (size_t)(nt * 16 + l15) * S_ + kb + quad * 8;
#pragma unroll
      for (int kt2 = 0; kt2 < 2; ++kt2)
        oacc[nt] = __builtin_amdgcn_mfma_f32_16x16x32_bf16(
            ap[kt2], *(const s16x8*)(vp + kt2 * 32), oacc[nt], 0, 0, 0);
    }
  }

  // ---- 4-way cross-wave merge, chunked 32 cols at a time ----
  if (l15 == 0) {
#pragma unroll
    for (int r = 0; r < 4; ++r) {
      mlds[w * 16 + quad * 4 + r] = m_r[r];
      llds[w * 16 + quad * 4 + r] = l_r[r];
    }
  }
  __syncthreads();

  const int row = tid >> 4;        // 0..15
  const int c2 = (tid & 15) * 2;   // 0,2,..30 within a 32-col chunk
  float mw[4];
#pragma unroll
  for (int w2 = 0; w2 < 4; ++w2) mw[w2] = mlds[w2 * 16 + row];
  float ms = fmaxf(fmaxf(mw[0], mw[1]), fmaxf(mw[2], mw[3]));
  float fw[4], lf = 0.f;
#pragma unroll
  for (int w2 = 0; w2 < 4; ++w2) {
    fw[w2] = exp2f((mw[w2] - ms) * L2E);
    lf += fw[w2] * llds[w2 * 16 + row];
  }
  const float invl = 1.0f / lf;

#pragma unroll
  for (int c = 0; c < 4; ++c) {
#pragma unroll
    for (int j = 0; j < 2; ++j) {
      int nt = 2 * c + j;
#pragma unroll
      for (int r = 0; r < 4; ++r)
        Ob[(w * 16 + quad * 4 + r) * 33 + j * 16 + l15] = oacc[nt][r];
    }
    __syncthreads();
    float o0 = 0.f, o1 = 0.f;
#pragma unroll
    for (int w2 = 0; w2 < 4; ++w2) {
      o0 += fw[w2] * Ob[(w2 * 16 + row) * 33 + c2];
      o1 += fw[w2] * Ob[(w2 * 16 + row) * 33 + c2 + 1];
    }
    float* op = out + bo + (size_t)(q0 + row) * H_ + c * 32 + c2;
    op[0] = o0 * invl;
    op[1] = o1 * invl;
    __syncthreads();  // buffer reused next chunk
  }
}

// ---------------------------------------------------------------------------
extern "C" void kernel_launch(void* const* d_in, const int* in_sizes, int n_in,
                              void* d_out, int out_size, void* d_ws, size_t ws_size,
                              hipStream_t stream) {
  const float* x  = (const float*)d_in[0];
  const float* Wq = (const float*)d_in[1];
  const float* bq = (const float*)d_in[2];
  const float* Wk = (const float*)d_in[3];
  const float* bk = (const float*)d_in[4];
  const float* Wv = (const float*)d_in[5];
  const float* bv = (const float*)d_in[6];

  // ws layout: Wt (384*2048 bf16) | Q | K | Vt (each B*S*H bf16) ~= 13.5 MB
  short* Wt = (short*)d_ws;
  short* Q  = Wt + (size_t)384 * E_;
  short* K  = Q + (size_t)B_ * S_ * H_;
  short* Vt = K + (size_t)B_ * S_ * H_;
  float* out = (float*)d_out;

  hipLaunchKernelGGL(prep_weights, dim3(64 * 4, 3), dim3(256), 0, stream,
                     Wq, Wk, Wv, Wt);
  hipLaunchKernelGGL(qkv_gemm, dim3((B_ * S_) / 32 * 2), dim3(256), 0, stream,
                     x, Wt, bq, bk, bv, Q, K, Vt);
  hipLaunchKernelGGL(flash_attn, dim3((S_ / 16) * B_), dim3(256), 0, stream,
                     Q, K, Vt, out);
}

// Round 7
// 378.520 us; speedup vs baseline: 1.2797x; 1.0430x over previous
//
#include <hip/hip_runtime.h>

#define B_ 4
#define S_ 4096
#define E_ 2048
#define H_ 128

using f32x4 = __attribute__((ext_vector_type(4))) float;
using s16x8 = __attribute__((ext_vector_type(8))) short;
using s16x4 = __attribute__((ext_vector_type(4))) short;

// fp32 -> bf16 bits, round-to-nearest-even
__device__ __forceinline__ short f2bf(float f) {
  unsigned u = __float_as_uint(f);
  u += 0x7FFFu + ((u >> 16) & 1u);
  return (short)(u >> 16);
}

// 16-lane (row) rotate via DPP: VALU-speed cross-lane, no DS pipe.
// row_ror:n ctrl = 0x120 | n. Butterfly over {8,4,2,1} converges all 16 lanes.
template <int CTRL>
__device__ __forceinline__ float dpp_rot(float v) {
  return __int_as_float(__builtin_amdgcn_update_dpp(
      0, __float_as_int(v), CTRL, 0xF, 0xF, false));
}
__device__ __forceinline__ float rowmax16(float v) {
  v = fmaxf(v, dpp_rot<0x128>(v));  // ror 8
  v = fmaxf(v, dpp_rot<0x124>(v));  // ror 4
  v = fmaxf(v, dpp_rot<0x122>(v));  // ror 2
  v = fmaxf(v, dpp_rot<0x121>(v));  // ror 1
  return v;
}
__device__ __forceinline__ float rowsum16(float v) {
  v += dpp_rot<0x128>(v);
  v += dpp_rot<0x124>(v);
  v += dpp_rot<0x122>(v);
  v += dpp_rot<0x121>(v);
  return v;
}

// ---------------------------------------------------------------------------
// Kernel 1: W (E x H fp32) x3 -> Wt (384 x 2048 bf16) via LDS tile transpose.
// ---------------------------------------------------------------------------
__global__ __launch_bounds__(256) void prep_weights(
    const float* __restrict__ Wq, const float* __restrict__ Wk,
    const float* __restrict__ Wv, short* __restrict__ Wt) {
  __shared__ float T[32 * 33];
  int p = blockIdx.y;
  const float* W = (p == 0) ? Wq : ((p == 1) ? Wk : Wv);
  int e0 = (blockIdx.x & 63) * 32;
  int h0 = (blockIdx.x >> 6) * 32;
  int r = threadIdx.x >> 5;
  int c = threadIdx.x & 31;
#pragma unroll
  for (int i = 0; i < 4; ++i) {
    int e = r + 8 * i;
    T[c * 33 + e] = W[(size_t)(e0 + e) * H_ + h0 + c];
  }
  __syncthreads();
#pragma unroll
  for (int i = 0; i < 4; ++i) {
    int h = r + 8 * i;
    Wt[(size_t)(p * H_ + h0 + h) * E_ + e0 + c] = f2bf(T[h * 33 + c]);
  }
}

// ---------------------------------------------------------------------------
// Kernel 2: fused QKV projection GEMM, BK=64 (unchanged from R6).
// ---------------------------------------------------------------------------
__global__ __launch_bounds__(256) void qkv_gemm(
    const float* __restrict__ x, const short* __restrict__ Wt,
    const float* __restrict__ bq, const float* __restrict__ bk,
    const float* __restrict__ bv,
    short* __restrict__ Q, short* __restrict__ K, short* __restrict__ Vt) {
  __shared__ __attribute__((aligned(16))) short xa[32 * 72];
  __shared__ __attribute__((aligned(16))) short wb[192 * 72];

  const int tid = threadIdx.x;
  const int wave = tid >> 6;
  const int lane = tid & 63;
  const int l15 = lane & 15;
  const int quad = lane >> 4;
  const int row0 = (blockIdx.x >> 1) * 32;
  const int nc0 = (blockIdx.x & 1) * 192;

  f32x4 acc[2][3];
#pragma unroll
  for (int mg = 0; mg < 2; ++mg)
#pragma unroll
    for (int nt = 0; nt < 3; ++nt) acc[mg][nt] = (f32x4){0.f, 0.f, 0.f, 0.f};

  const int sr = tid >> 3;
  const int sc8 = (tid & 7) * 8;
  const int wr = tid >> 2;
  const int wo = (tid & 3) * 16;
  const float* xp = x + (size_t)(row0 + sr) * E_ + sc8;
  const short* wp = Wt + (size_t)(nc0 + wr) * E_ + wo;

  float4 xf0 = *(const float4*)(xp);
  float4 xf1 = *(const float4*)(xp + 4);
  s16x8 wreg[6];
#pragma unroll
  for (int j = 0; j < 3; ++j) {
    wreg[2 * j]     = *(const s16x8*)(wp + (size_t)(64 * j) * E_);
    wreg[2 * j + 1] = *(const s16x8*)(wp + (size_t)(64 * j) * E_ + 8);
  }

  for (int it = 0; it < 32; ++it) {
    __syncthreads();
    {
      s16x8 xv;
      xv[0] = f2bf(xf0.x); xv[1] = f2bf(xf0.y); xv[2] = f2bf(xf0.z); xv[3] = f2bf(xf0.w);
      xv[4] = f2bf(xf1.x); xv[5] = f2bf(xf1.y); xv[6] = f2bf(xf1.z); xv[7] = f2bf(xf1.w);
      *(s16x8*)&xa[sr * 72 + sc8] = xv;
    }
#pragma unroll
    for (int j = 0; j < 3; ++j) {
      *(s16x8*)&wb[(wr + 64 * j) * 72 + wo] = wreg[2 * j];
      *(s16x8*)&wb[(wr + 64 * j) * 72 + wo + 8] = wreg[2 * j + 1];
    }
    __syncthreads();

    if (it < 31) {
      const int k0n = (it + 1) * 64;
      xf0 = *(const float4*)(xp + k0n);
      xf1 = *(const float4*)(xp + k0n + 4);
#pragma unroll
      for (int j = 0; j < 3; ++j) {
        wreg[2 * j]     = *(const s16x8*)(wp + (size_t)(64 * j) * E_ + k0n);
        wreg[2 * j + 1] = *(const s16x8*)(wp + (size_t)(64 * j) * E_ + k0n + 8);
      }
    }

#pragma unroll
    for (int kc = 0; kc < 2; ++kc) {
      const int ko = kc * 32 + quad * 8;
      s16x8 af[2], bfr[3];
#pragma unroll
      for (int mg = 0; mg < 2; ++mg)
        af[mg] = *(const s16x8*)&xa[(mg * 16 + l15) * 72 + ko];
#pragma unroll
      for (int nt = 0; nt < 3; ++nt)
        bfr[nt] = *(const s16x8*)&wb[(wave * 48 + nt * 16 + l15) * 72 + ko];
#pragma unroll
      for (int mg = 0; mg < 2; ++mg)
#pragma unroll
        for (int nt = 0; nt < 3; ++nt)
          acc[mg][nt] = __builtin_amdgcn_mfma_f32_16x16x32_bf16(
              af[mg], bfr[nt], acc[mg][nt], 0, 0, 0);
    }
  }

  const float scale = 0.08838834764831845f;  // 1/sqrt(128), folded into Q
  const int b = row0 >> 12;
  const int s_base = row0 & (S_ - 1);
#pragma unroll
  for (int nt = 0; nt < 3; ++nt) {
    int col = nc0 + wave * 48 + nt * 16 + l15;
    int p = col >> 7;
    int h = col & (H_ - 1);
    if (p == 2) {
      float bsv = bv[h];
#pragma unroll
      for (int mg = 0; mg < 2; ++mg) {
        int s0 = s_base + mg * 16 + quad * 4;
        s16x4 vv;
#pragma unroll
        for (int r = 0; r < 4; ++r) vv[r] = f2bf(acc[mg][nt][r] + bsv);
        *(s16x4*)&Vt[((size_t)b * H_ + h) * S_ + s0] = vv;
      }
    } else if (p == 0) {
      float bsv = bq[h];
#pragma unroll
      for (int mg = 0; mg < 2; ++mg)
#pragma unroll
        for (int r = 0; r < 4; ++r) {
          int row = row0 + mg * 16 + quad * 4 + r;
          Q[(size_t)row * H_ + h] = f2bf((acc[mg][nt][r] + bsv) * scale);
        }
    } else {
      float bsv = bk[h];
#pragma unroll
      for (int mg = 0; mg < 2; ++mg)
#pragma unroll
        for (int r = 0; r < 4; ++r) {
          int row = row0 + mg * 16 + quad * 4 + r;
          K[(size_t)row * H_ + h] = f2bf(acc[mg][nt][r] + bsv);
        }
    }
  }
}

// ---------------------------------------------------------------------------
// Kernel 3: causal flash attention, 8-WAY k-split (512 thr), DPP softmax
// reductions (row_ror butterfly, VALU-speed — replaces 8 ds_bpermutes ~1000
// cyc of the per-iter critical path). NO min-waves hint (R4/R5: hints force
// VGPR clamp + scratch spills; natural alloc was 72 VGPR, spill-free).
// 1024 blocks x 8 waves = 8192 waves (2x R6 supply). LDS 36.3 KB.
// ---------------------------------------------------------------------------
__global__ __launch_bounds__(512) void flash_attn(
    const short* __restrict__ Qb, const short* __restrict__ Kb,
    const short* __restrict__ Vtb, float* __restrict__ out) {
  __shared__ __attribute__((aligned(16))) short p_all[8 * 16 * 72];  // 18432 B
  __shared__ float Ob[8 * 16 * 33];                                  // 16896 B
  __shared__ float mlds[128], llds[128];                             //  1024 B

  const int tid = threadIdx.x;
  const int w = tid >> 6;
  const int lane = tid & 63;
  const int l15 = lane & 15;
  const int quad = lane >> 4;
  const int t = 255 - (blockIdx.x >> 2);  // heavy q-tiles first
  const int b = blockIdx.x & 3;
  const int q0 = t * 16;
  const size_t bo = (size_t)b * S_ * H_;
  const short* Vb = Vtb + (size_t)b * H_ * S_;  // [h][s]
  const float L2E = 1.4426950408889634f;
  const int nk = (t >> 2) + 1;  // 64-key tiles covering causal range

  short* p_lds = &p_all[w * (16 * 72)];

  s16x8 aq[4];
#pragma unroll
  for (int kt = 0; kt < 4; ++kt)
    aq[kt] = *(const s16x8*)(Qb + bo + (size_t)(q0 + l15) * H_ + kt * 32 + quad * 8);

  f32x4 oacc[8];
#pragma unroll
  for (int nt = 0; nt < 8; ++nt) oacc[nt] = (f32x4){0.f, 0.f, 0.f, 0.f};
  float m_r[4], l_r[4];
#pragma unroll
  for (int r = 0; r < 4; ++r) { m_r[r] = -3.0e38f; l_r[r] = 0.f; }

  for (int i = w; i < nk; i += 8) {
    const int kb = i * 64;
    // scores S = Q @ K^T (16 x 64), Q pre-scaled
    f32x4 sc[4];
#pragma unroll
    for (int nt = 0; nt < 4; ++nt) {
      f32x4 a = (f32x4){0.f, 0.f, 0.f, 0.f};
      const short* kp = Kb + bo + (size_t)(kb + nt * 16 + l15) * H_ + quad * 8;
#pragma unroll
      for (int kt = 0; kt < 4; ++kt)
        a = __builtin_amdgcn_mfma_f32_16x16x32_bf16(
            aq[kt], *(const s16x8*)(kp + kt * 32), a, 0, 0, 0);
      sc[nt] = a;
    }
    if (i == nk - 1) {  // diagonal k-tile: causal mask
      const int qloc = (t & 3) * 16 + quad * 4;
#pragma unroll
      for (int nt = 0; nt < 4; ++nt)
#pragma unroll
        for (int r = 0; r < 4; ++r)
          if (nt * 16 + l15 > qloc + r) sc[nt][r] = -3.0e38f;
    }
    // row max over 64 cols: 4 in-register + DPP 16-lane butterfly
    float vm[4], al[4], rs[4];
#pragma unroll
    for (int r = 0; r < 4; ++r) {
      vm[r] = rowmax16(
          fmaxf(fmaxf(sc[0][r], sc[1][r]), fmaxf(sc[2][r], sc[3][r])));
      float mn = fmaxf(m_r[r], vm[r]);
      al[r] = exp2f((m_r[r] - mn) * L2E);
      m_r[r] = mn;
    }
#pragma unroll
    for (int r = 0; r < 4; ++r) {
      float s = 0.f;
#pragma unroll
      for (int nt = 0; nt < 4; ++nt) {
        float pv = exp2f((sc[nt][r] - m_r[r]) * L2E);
        sc[nt][r] = pv;
        s += pv;
      }
      rs[r] = rowsum16(s);
      l_r[r] = l_r[r] * al[r] + rs[r];
    }

    // P (C-layout) -> per-wave LDS (bf16, A-layout read below)
    __asm__ volatile("s_waitcnt lgkmcnt(0)" ::: "memory");  // WAR vs prior reads
#pragma unroll
    for (int nt = 0; nt < 4; ++nt)
#pragma unroll
      for (int r = 0; r < 4; ++r)
        p_lds[(quad * 4 + r) * 72 + nt * 16 + l15] = f2bf(sc[nt][r]);

    // rescale O while the LDS writes land (hides write latency)
#pragma unroll
    for (int nt = 0; nt < 8; ++nt)
#pragma unroll
      for (int r = 0; r < 4; ++r) oacc[nt][r] *= al[r];

    __asm__ volatile("s_waitcnt lgkmcnt(0)" ::: "memory");  // RAW: writes visible
    s16x8 ap[2];
#pragma unroll
    for (int kt2 = 0; kt2 < 2; ++kt2)
      ap[kt2] = *(const s16x8*)&p_lds[l15 * 72 + kt2 * 32 + quad * 8];

    // O += P @ V from Vt[h][s]
#pragma unroll
    for (int nt = 0; nt < 8; ++nt) {
      const short* vp = Vb + (size_t)(nt * 16 + l15) * S_ + kb + quad * 8;
#pragma unroll
      for (int kt2 = 0; kt2 < 2; ++kt2)
        oacc[nt] = __builtin_amdgcn_mfma_f32_16x16x32_bf16(
            ap[kt2], *(const s16x8*)(vp + kt2 * 32), oacc[nt], 0, 0, 0);
    }
  }

  // ---- 8-way cross-wave merge, chunked 32 cols at a time ----
  if (l15 == 0) {
#pragma unroll
    for (int r = 0; r < 4; ++r) {
      mlds[w * 16 + quad * 4 + r] = m_r[r];
      llds[w * 16 + quad * 4 + r] = l_r[r];
    }
  }
  __syncthreads();

  const int row = tid >> 5;   // 0..15
  const int col = tid & 31;   // 0..31
  float mw[8];
#pragma unroll
  for (int w2 = 0; w2 < 8; ++w2) mw[w2] = mlds[w2 * 16 + row];
  float ms = mw[0];
#pragma unroll
  for (int w2 = 1; w2 < 8; ++w2) ms = fmaxf(ms, mw[w2]);
  float fw[8], lf = 0.f;
#pragma unroll
  for (int w2 = 0; w2 < 8; ++w2) {
    fw[w2] = exp2f((mw[w2] - ms) * L2E);
    lf += fw[w2] * llds[w2 * 16 + row];
  }
  const float invl = 1.0f / lf;

#pragma unroll
  for (int c = 0; c < 4; ++c) {
    // each wave writes its cols [c*32, c*32+32) = acc tiles nt=2c, 2c+1
#pragma unroll
    for (int j = 0; j < 2; ++j) {
      int nt = 2 * c + j;
#pragma unroll
      for (int r = 0; r < 4; ++r)
        Ob[(w * 16 + quad * 4 + r) * 33 + j * 16 + l15] = oacc[nt][r];
    }
    __syncthreads();
    float o = 0.f;
#pragma unroll
    for (int w2 = 0; w2 < 8; ++w2) o += fw[w2] * Ob[(w2 * 16 + row) * 33 + col];
    out[bo + (size_t)(q0 + row) * H_ + c * 32 + col] = o * invl;
    __syncthreads();  // buffer reused next chunk
  }
}

// ---------------------------------------------------------------------------
extern "C" void kernel_launch(void* const* d_in, const int* in_sizes, int n_in,
                              void* d_out, int out_size, void* d_ws, size_t ws_size,
                              hipStream_t stream) {
  const float* x  = (const float*)d_in[0];
  const float* Wq = (const float*)d_in[1];
  const float* bq = (const float*)d_in[2];
  const float* Wk = (const float*)d_in[3];
  const float* bk = (const float*)d_in[4];
  const float* Wv = (const float*)d_in[5];
  const float* bv = (const float*)d_in[6];

  // ws layout: Wt (384*2048 bf16) | Q | K | Vt (each B*S*H bf16) ~= 13.5 MB
  short* Wt = (short*)d_ws;
  short* Q  = Wt + (size_t)384 * E_;
  short* K  = Q + (size_t)B_ * S_ * H_;
  short* Vt = K + (size_t)B_ * S_ * H_;
  float* out = (float*)d_out;

  hipLaunchKernelGGL(prep_weights, dim3(64 * 4, 3), dim3(256), 0, stream,
                     Wq, Wk, Wv, Wt);
  hipLaunchKernelGGL(qkv_gemm, dim3((B_ * S_) / 32 * 2), dim3(256), 0, stream,
                     x, Wt, bq, bk, bv, Q, K, Vt);
  hipLaunchKernelGGL(flash_attn, dim3((S_ / 16) * B_), dim3(512), 0, stream,
                     Q, K, Vt, out);
}